// Round 4
// baseline (285.276 us; speedup 1.0000x reference)
//
#include <hip/hip_runtime.h>

// out[..., m] = b[..., m] + ALPHA * b[..., m+1]  (m < 39);  out[..., 39] = b[..., 39]
// b: (16, 65536, 40) float32, flat n = 41,943,040 = 10,485,760 float4s.
// Row = 40 floats = 10 float4s -> within a float4 (index i) only elem 3 can be
// the row-last coeff, exactly when i % 10 == 9.
//
// Structure: loop-free, 4 float4s per thread at stride T = n4/4. T % 10 == 0 for
// the bench shape, so all four indices share one %10 phase. 4 independent loads
// issue back-to-back (no loop-carried vmcnt serialization). NORMAL stores:
// round-3 showed nontemporal 16B stores bypass L2 write-combining and halve
// write throughput (1.6 TB/s vs 6.65 TB/s fill).

static constexpr float kAlpha = 0.42f;
typedef float f32x4 __attribute__((ext_vector_type(4)));

__global__ void __launch_bounds__(256)
b2mc_kernel(const float* __restrict__ b, float* __restrict__ out, int n4, int T) {
    const int t = blockIdx.x * blockDim.x + threadIdx.x;
    if (t >= T) return;
    const f32x4* __restrict__ b4 = reinterpret_cast<const f32x4*>(b);
    f32x4* __restrict__ o4 = reinterpret_cast<f32x4*>(out);

    const int i0 = t;
    const int i1 = t + T;
    const int i2 = t + 2 * T;
    const int i3 = t + 3 * T;

    // All 4 loads in flight before any dependent work.
    f32x4 v0 = b4[i0];
    f32x4 v1 = b4[i1];
    f32x4 v2 = b4[i2];
    f32x4 v3 = b4[i3];

    // T % 10 == 0 => all four indices have the same phase mod 10.
    const bool re = (t % 10) == 9;            // elem 3 is m==39 of its row
    const bool lane63 = ((threadIdx.x & 63) == 63);

    // Neighbor float4's elem 0 via cross-lane; lane 63 falls back to a real
    // load (line is being fetched by the adjacent wave anyway -> L1/L2 hit).
    float nxt0 = __shfl_down(v0.x, 1);
    float nxt1 = __shfl_down(v1.x, 1);
    float nxt2 = __shfl_down(v2.x, 1);
    float nxt3 = __shfl_down(v3.x, 1);
    if (lane63 && !re) {                      // !re => i_j+1 in bounds (n%40==0)
        nxt0 = b[4 * i0 + 4];
        nxt1 = b[4 * i1 + 4];
        nxt2 = b[4 * i2 + 4];
        nxt3 = b[4 * i3 + 4];
    }

    f32x4 r0, r1, r2, r3;
    r0.x = fmaf(kAlpha, v0.y, v0.x);
    r0.y = fmaf(kAlpha, v0.z, v0.y);
    r0.z = fmaf(kAlpha, v0.w, v0.z);
    r0.w = re ? v0.w : fmaf(kAlpha, nxt0, v0.w);
    r1.x = fmaf(kAlpha, v1.y, v1.x);
    r1.y = fmaf(kAlpha, v1.z, v1.y);
    r1.z = fmaf(kAlpha, v1.w, v1.z);
    r1.w = re ? v1.w : fmaf(kAlpha, nxt1, v1.w);
    r2.x = fmaf(kAlpha, v2.y, v2.x);
    r2.y = fmaf(kAlpha, v2.z, v2.y);
    r2.z = fmaf(kAlpha, v2.w, v2.z);
    r2.w = re ? v2.w : fmaf(kAlpha, nxt2, v2.w);
    r3.x = fmaf(kAlpha, v3.y, v3.x);
    r3.y = fmaf(kAlpha, v3.z, v3.y);
    r3.z = fmaf(kAlpha, v3.w, v3.z);
    r3.w = re ? v3.w : fmaf(kAlpha, nxt3, v3.w);

    o4[i0] = r0;
    o4[i1] = r1;
    o4[i2] = r2;
    o4[i3] = r3;
}

extern "C" void kernel_launch(void* const* d_in, const int* in_sizes, int n_in,
                              void* d_out, int out_size, void* d_ws, size_t ws_size,
                              hipStream_t stream) {
    const float* b = (const float*)d_in[0];
    float* out = (float*)d_out;
    const int n = in_sizes[0];       // 41,943,040
    const int n4 = n / 4;            // 10,485,760 float4s (divisible by 4 and 10)
    const int T = n4 / 4;            // 2,621,440 threads, stride between chunks
    const int block = 256;
    const int grid = (T + block - 1) / block;   // 10,240 blocks
    b2mc_kernel<<<grid, block, 0, stream>>>(b, out, n4, T);
}

// Round 9
// 277.709 us; speedup vs baseline: 1.0273x; 1.0273x over previous
//
#include <hip/hip_runtime.h>

// out[..., m] = b[..., m] + ALPHA * b[..., m+1]  (m < 39);  out[..., 39] = b[..., 39]
// b: (16, 65536, 40) float32, flat n = 41,943,040 = 10,485,760 float4s.
// Row = 40 floats = 10 float4s -> within a float4 (index i) only elem 3 can be
// the row-last coeff, exactly when i % 10 == 9.
//
// Structure (R5, resubmitted — four acquisition timeouts, never measured):
// flat, 4 float4s/thread at stride T = n4/4 (T%10==0 so one rowend flag per
// thread). The elem-3 neighbor comes from an extra scalar dword load (same
// cache line the adjacent lane loads -> L1 hit, ~0 extra HBM) instead of
// __shfl_down: removes the load->vmcnt->ds_bpermute->lgkmcnt serialization
// and the divergent lane-63 fallback of R4. All 8 loads issue independently;
// one wait; compute; 4 stores. Normal stores (R3 showed nontemporal 16B
// stores halve write BW: 1.6 vs 6.65 TB/s fill).

static constexpr float kAlpha = 0.42f;
typedef float f32x4 __attribute__((ext_vector_type(4)));

__global__ void __launch_bounds__(256)
b2mc_kernel(const float* __restrict__ b, float* __restrict__ out, int T) {
    const int t = blockIdx.x * blockDim.x + threadIdx.x;
    if (t >= T) return;
    const f32x4* __restrict__ b4 = reinterpret_cast<const f32x4*>(b);
    f32x4* __restrict__ o4 = reinterpret_cast<f32x4*>(out);

    const int i0 = t;
    const int i1 = t + T;
    const int i2 = t + 2 * T;
    const int i3 = t + 3 * T;

    // T % 10 == 0 => all four indices share one phase mod 10.
    const bool re = (t % 10) == 9;     // elem 3 is m==39 of its row
    // Neighbor scalar offset: +4 elements normally; clamped to +0 for rowend
    // lanes (value unused -> zeroed below) so the global-last float4 stays
    // in bounds.
    const int d = re ? 0 : 4;

    // 8 independent loads, all in flight before any dependent work.
    f32x4 v0 = b4[i0];
    f32x4 v1 = b4[i1];
    f32x4 v2 = b4[i2];
    f32x4 v3 = b4[i3];
    float n0 = b[4 * i0 + d];
    float n1 = b[4 * i1 + d];
    float n2 = b[4 * i2 + d];
    float n3 = b[4 * i3 + d];

    if (re) { n0 = 0.0f; n1 = 0.0f; n2 = 0.0f; n3 = 0.0f; }

    f32x4 r0, r1, r2, r3;
    r0.x = fmaf(kAlpha, v0.y, v0.x);
    r0.y = fmaf(kAlpha, v0.z, v0.y);
    r0.z = fmaf(kAlpha, v0.w, v0.z);
    r0.w = fmaf(kAlpha, n0, v0.w);
    r1.x = fmaf(kAlpha, v1.y, v1.x);
    r1.y = fmaf(kAlpha, v1.z, v1.y);
    r1.z = fmaf(kAlpha, v1.w, v1.z);
    r1.w = fmaf(kAlpha, n1, v1.w);
    r2.x = fmaf(kAlpha, v2.y, v2.x);
    r2.y = fmaf(kAlpha, v2.z, v2.y);
    r2.z = fmaf(kAlpha, v2.w, v2.z);
    r2.w = fmaf(kAlpha, n2, v2.w);
    r3.x = fmaf(kAlpha, v3.y, v3.x);
    r3.y = fmaf(kAlpha, v3.z, v3.y);
    r3.z = fmaf(kAlpha, v3.w, v3.z);
    r3.w = fmaf(kAlpha, n3, v3.w);

    o4[i0] = r0;
    o4[i1] = r1;
    o4[i2] = r2;
    o4[i3] = r3;
}

extern "C" void kernel_launch(void* const* d_in, const int* in_sizes, int n_in,
                              void* d_out, int out_size, void* d_ws, size_t ws_size,
                              hipStream_t stream) {
    const float* b = (const float*)d_in[0];
    float* out = (float*)d_out;
    const int n = in_sizes[0];       // 41,943,040
    const int n4 = n / 4;            // 10,485,760 float4s (divisible by 4 and 10)
    const int T = n4 / 4;            // 2,621,440 threads, chunk stride
    const int block = 256;
    const int grid = (T + block - 1) / block;   // 10,240 blocks
    b2mc_kernel<<<grid, block, 0, stream>>>(b, out, T);
}